// Round 10
// baseline (1153.596 us; speedup 1.0000x reference)
//
#include <hip/hip_runtime.h>
#include <stdint.h>

#define N_SAMP  2000000
#define NF4     500000          // float4 groups
#define NSTEP   32
#define INV_N   (1.0/2000000.0)
#define NBUCK   64
#define GRID    1024
#define NWORK   1023
#define BLKSZ   256

#define OUT_BE  2000000
#define OUT_BP  2000204
#define OUT_ETA 2000408
#define OUT_TH  2000606
#define OUT_DH  2000804

// ws doubles layout
#define O_JB    0
#define O_SYB   (37*NBUCK)
#define O_SXB   (O_SYB + NSTEP*10*NBUCK)
#define O_END   (O_SXB + NSTEP*10*NBUCK)
// u32 region: [0..7] COEFP f32, [8..15] COEFC f32, [32..63] leaf0,
// [64..95] leafP, [96..127] leafC, [128..639] seqP x32 (stride 16),
// [640..1151] seqC x32 (stride 16)
#define WS_BYTES (O_END*8 + 1152*4)

#define CFENCE() __atomic_signal_fence(__ATOMIC_SEQ_CST)
#define WAITVM() __builtin_amdgcn_s_waitcnt(0)

__device__ inline uint32_t uld(const uint32_t* p) {
  return __hip_atomic_load(p, __ATOMIC_RELAXED, __HIP_MEMORY_SCOPE_AGENT);
}
__device__ inline void ust(uint32_t* p, uint32_t v) {
  __hip_atomic_store(p, v, __ATOMIC_RELAXED, __HIP_MEMORY_SCOPE_AGENT);
}
__device__ inline void uadd(uint32_t* p, uint32_t v) {
  __hip_atomic_fetch_add(p, v, __ATOMIC_RELAXED, __HIP_MEMORY_SCOPE_AGENT);
}
__device__ inline double dld(const double* p) {
  return __hip_atomic_load(p, __ATOMIC_RELAXED, __HIP_MEMORY_SCOPE_AGENT);
}
__device__ inline float fld(const float* p) {
  return __hip_atomic_load(p, __ATOMIC_RELAXED, __HIP_MEMORY_SCOPE_AGENT);
}
__device__ inline void fst(float* p, float v) {
  __hip_atomic_store(p, v, __ATOMIC_RELAXED, __HIP_MEMORY_SCOPE_AGENT);
}

// ---------------- threefry2x32 core cipher, bit-exact vs JAX ----------------
__host__ __device__ inline void threefry2x32(uint32_t k0, uint32_t k1,
                                             uint32_t c0, uint32_t c1,
                                             uint32_t* o0, uint32_t* o1) {
  uint32_t ks2 = k0 ^ k1 ^ 0x1BD11BDAu;
  uint32_t x0 = c0 + k0;
  uint32_t x1 = c1 + k1;
#define TF_ROT(x, d) (((x) << (d)) | ((x) >> (32 - (d))))
#define TF_R(a,b,c,d, ka, kb, inc) \
  x0 += x1; x1 = TF_ROT(x1, a); x1 ^= x0; \
  x0 += x1; x1 = TF_ROT(x1, b); x1 ^= x0; \
  x0 += x1; x1 = TF_ROT(x1, c); x1 ^= x0; \
  x0 += x1; x1 = TF_ROT(x1, d); x1 ^= x0; \
  x0 += (ka); x1 += (kb) + (inc);
  TF_R(13,15,26,6,  k1,  ks2, 1u)
  TF_R(17,29,16,24, ks2, k0,  2u)
  TF_R(13,15,26,6,  k0,  k1,  3u)
  TF_R(17,29,16,24, k1,  ks2, 4u)
  TF_R(13,15,26,6,  ks2, k0,  5u)
#undef TF_R
#undef TF_ROT
  *o0 = x0; *o1 = x1;
}

// bits -> N(0,1), jax.random.normal f32 path (partitionable bits pre-XOR-folded)
__device__ inline float bits_to_normal(uint32_t bits) {
  float f = __uint_as_float((bits >> 9) | 0x3f800000u) - 1.0f;
  const float lo = -0.99999994f;
  float u = f * 2.0f + lo;
  u = fmaxf(lo, u);
  float w = -log1pf(-u * u);
  float p;
  if (w < 5.0f) {
    w = w - 2.5f;
    p = 2.81022636e-08f;
    p = fmaf(p, w, 3.43273939e-07f);
    p = fmaf(p, w, -3.5233877e-06f);
    p = fmaf(p, w, -4.39150654e-06f);
    p = fmaf(p, w, 0.00021858087f);
    p = fmaf(p, w, -0.00125372503f);
    p = fmaf(p, w, -0.00417768164f);
    p = fmaf(p, w, 0.246640727f);
    p = fmaf(p, w, 1.50140941f);
  } else {
    w = sqrtf(w) - 3.0f;
    p = -0.000200214257f;
    p = fmaf(p, w, 0.000100950558f);
    p = fmaf(p, w, 0.00134934322f);
    p = fmaf(p, w, -0.00367342844f);
    p = fmaf(p, w, 0.00573950773f);
    p = fmaf(p, w, -0.0076224613f);
    p = fmaf(p, w, 0.00943887047f);
    p = fmaf(p, w, 1.00167406f);
    p = fmaf(p, w, 2.83297682f);
  }
  return __uint_as_float(0x3FB504F3u) * (p * u);
}

// lane-distributed 6x6 Gaussian elimination (wave 0). S replicated; rv = rhs
// for lane<6. Lane r<6 returns solution[r].
__device__ inline double wave_gauss6(const double S[11], double rv, int lane) {
  int r = (lane < 6) ? lane : 0;
  double row[6];
#pragma unroll
  for (int j = 0; j < 6; j++) row[j] = (double)((r + 1) * (j + 1)) * S[r + j];
  row[r] *= 1.001;                        // REG = (1e-3, 0, 0)
#pragma unroll
  for (int c = 0; c < 6; c++) {
    double pr[6], prh;
#pragma unroll
    for (int j = 0; j < 6; j++) pr[j] = __shfl(row[j], c, 64);
    prh = __shfl(rv, c, 64);
    if (lane > c && lane < 6) {
      double f = row[c] / pr[c];
#pragma unroll
      for (int j = 0; j < 6; j++) row[j] -= f * pr[j];
      rv -= f * prh;
    }
  }
  double xv = 0.0;
#pragma unroll
  for (int rr = 5; rr >= 0; rr--) {
    double cand = rv / row[rr];
    double xr = __shfl(cand, rr, 64);
    if (lane == rr) xv = xr;
    if (lane < rr) rv -= row[rr] * xr;
  }
  return xv;
}

// solver: wait until sum of 32 leaf counters reaches target
__device__ inline void wait_leaves(const uint32_t* leaf, uint32_t target, int lane) {
  for (;;) {
    uint32_t v = uld(&leaf[lane & 31]);
#pragma unroll
    for (int off = 16; off; off >>= 1) v += __shfl_xor(v, off, 64);
    if (v >= target) break;
    __builtin_amdgcn_s_sleep(2);
  }
  CFENCE();
}

// solver: replicated mean-moments from 64 buckets x 10 quantities
__device__ inline void get_S(const double* B, int lane, double S[11]) {
  S[0] = 1.0;
#pragma unroll
  for (int q = 0; q < 10; q++) {
    double s = dld(&B[q * NBUCK + lane]);
#pragma unroll
    for (int off = 32; off; off >>= 1) s += __shfl_xor(s, off, 64);
    S[q + 1] = s * INV_N;
  }
}

// worker: f32 block-reduce of NQ quantities -> f64 bucket atomics (t<NQ)
template <int NQ>
__device__ inline void block_bucket(float acc[NQ], double* __restrict__ buck,
                                    float smf[4][37], int lane, int wid, int t,
                                    int bidx) {
#pragma unroll
  for (int q = 0; q < NQ; q++) {
    float v = acc[q];
#pragma unroll
    for (int off = 32; off; off >>= 1) v += __shfl_down(v, off, 64);
    if (lane == 0) smf[wid][q] = v;
  }
  __syncthreads();
  if (t < NQ) {
    double s = (double)smf[0][t] + (double)smf[1][t] +
               (double)smf[2][t] + (double)smf[3][t];
    atomicAdd(&buck[t * NBUCK + bidx], s);
  }
}

__global__ __launch_bounds__(BLKSZ, 4) void k_all(
    const float* __restrict__ x1g, const float* __restrict__ x0g,
    const float* __restrict__ xkg, const float* __restrict__ tg,
    float* __restrict__ out, double* __restrict__ WD, uint32_t* __restrict__ WU) {
  __shared__ float smf[4][37];
  __shared__ float sC[8];
  __shared__ double sMsc[37];
  __shared__ float sF[NSTEP * 20];
  __shared__ uint32_t sK[NSTEP][2];

  const int t = threadIdx.x;
  const int lane = t & 63, wid = t >> 6;
  double* JB  = WD + O_JB;
  double* SYB = WD + O_SYB;
  double* SXB = WD + O_SXB;
  float* COEFP = (float*)WU;
  float* COEFC = (float*)(WU + 8);
  uint32_t* leaf0 = WU + 32;
  uint32_t* leafP = WU + 64;
  uint32_t* leafC = WU + 96;
  uint32_t* seqP  = WU + 128;   // 32 replicas, stride 16 (64B lines)
  uint32_t* seqC  = WU + 640;

  if (blockIdx.x == 0) {
    // =========================== SOLVER (wave 0) ===========================
    if (t >= 64) return;
    wait_leaves(leaf0, NWORK, lane);
    for (int q = 0; q < 37; q++) {
      double s = dld(&JB[q * NBUCK + lane]);
#pragma unroll
      for (int off = 32; off; off >>= 1) s += __shfl_xor(s, off, 64);
      if (lane == 0) sMsc[q] = s * INV_N;
    }
#define MG(A, B_) (((A) == 0 && (B_) == 0) ? 1.0 : \
    sMsc[(((A) + (B_) + 2) * ((A) + (B_) - 1)) / 2 + (A)])
    if (lane < NSTEP) {
      const double Bd[7][7] = {
          {1,0,0,0,0,0,0},{1,1,0,0,0,0,0},{1,2,1,0,0,0,0},{1,3,3,1,0,0,0},
          {1,4,6,4,1,0,0},{1,5,10,10,5,1,0},{1,6,15,20,15,6,1}};
      int k = lane;
      float tk = tg[k], tk1 = tg[k + 1];
      float h = tk1 - tk;
      float ns = sqrtf(2.0f * h) * 0.5f;
      const float PI_F = 3.14159274f;
      double a  = (double)cosf((PI_F * tk) * 0.5f);
      double b  = (double)sinf((PI_F * tk) * 0.5f);
      double a1 = (double)cosf((PI_F * tk1) * 0.5f);
      double b1 = (double)sinf((PI_F * tk1) * 0.5f);
      const double C2 = (double)1.57079637f;
      double pa[7], pb[7], pa1[7], pb1[7];
      pa[0] = pb[0] = pa1[0] = pb1[0] = 1.0;
      for (int i = 1; i < 7; i++) {
        pa[i] = pa[i-1] * a;   pb[i] = pb[i-1] * b;
        pa1[i] = pa1[i-1] * a1; pb1[i] = pb1[i-1] * b1;
      }
      sF[k * 20 + 0] = h;
      sF[k * 20 + 1] = ns;
      for (int p = 1; p <= 6; p++) {
        double s_rhs = 0, s_bpe = 0, s_dt = 0;
        for (int j = 0; j < p; j++) {
          double term = -b * MG(j + 1, p - 1 - j) + a * MG(j, p - j);
          s_rhs += Bd[p-1][j] * pa[j]  * pb[p-1-j]  * term;
          s_dt  += Bd[p-1][j] * pa1[j] * pb1[p-1-j] * term;
        }
        for (int j = 0; j <= p; j++)
          s_bpe += Bd[p][j] * pa1[j] * pb1[p - j] * MG(j, p - j);
        float fr = (float)((double)p * C2 * s_rhs);
        float be = (float)s_bpe;
        sF[k * 20 + 2 + p - 1]  = fr;
        sF[k * 20 + 8 + p - 1]  = be;
        sF[k * 20 + 14 + p - 1] = (float)((double)p * C2 * s_dt);
        out[OUT_BE + (k + 1) * 6 + (p - 1)] = be;
        if (k == NSTEP - 1) out[OUT_BE + (NSTEP + 1) * 6 + (p - 1)] = be;
      }
    }
    if (lane < 6) {
      int p = lane + 1;
      out[OUT_BE + lane] = (float)MG(p, 0);
      out[OUT_BP + lane] = (float)sMsc[27 + lane];
    }
#undef MG
    // eta_0 solve + publish step-0 pred coefs
    {
      double S[11];
      S[0] = 1.0;
#pragma unroll
      for (int q = 0; q < 10; q++) S[q + 1] = sMsc[27 + q];
      double rv = (lane < 6) ? (double)sF[2 + lane] : 0.0;
      double xv = wave_gauss6(S, rv, lane);
      if (lane < 6) {
        out[OUT_ETA + lane] = (float)xv;
        fst(&COEFP[lane], (float)xv * (float)(lane + 1));
      }
      if (lane == 6) fst(&COEFP[6], sF[0]);
      if (lane == 7) fst(&COEFP[7], sF[1]);
      CFENCE(); WAITVM();
      if (lane < 32) ust(&seqP[lane * 16], 1u);
    }
    for (int k = 0; k < NSTEP; k++) {
      // theta solve after all pred buckets of step k
      wait_leaves(leafP, (uint32_t)(NWORK * (k + 1)), lane);
      {
        double S[11];
        get_S(SYB + k * 10 * NBUCK, lane, S);
        double rv = (lane < 6) ? ((double)sF[k*20 + 8 + lane] - S[lane + 1]) : 0.0;
        double xv = wave_gauss6(S, rv, lane);
        if (lane < 6) fst(&COEFC[lane], (float)xv * (float)(lane + 1));
        float h = sF[k * 20];
        float th = (float)xv / (h * 0.25f);
        if (lane < 6) {
          out[OUT_TH + k * 6 + lane] = th;
          if (k == NSTEP - 1) out[OUT_TH + NSTEP * 6 + lane] = th;
        }
        float contrib = (lane < 6) ? th * sF[k*20 + 14 + lane] : 0.f;
#pragma unroll
        for (int off = 4; off; off >>= 1) contrib += __shfl_down(contrib, off, 64);
        if (lane == 0) {
          float dH = -contrib;
          out[OUT_DH + k] = dH;
          if (k == NSTEP - 1) out[OUT_DH + NSTEP] = dH;
        }
        CFENCE(); WAITVM();
        if (lane < 32) ust(&seqC[lane * 16], (uint32_t)(k + 1));
      }
      // eta_{k+1} solve after all corr buckets of step k
      wait_leaves(leafC, (uint32_t)(NWORK * (k + 1)), lane);
      {
        double S[11];
        get_S(SXB + k * 10 * NBUCK, lane, S);
        if (lane < 6) {
          float bp = (float)S[lane + 1];
          out[OUT_BP + (k + 1) * 6 + lane] = bp;
          if (k == NSTEP - 1) out[OUT_BP + (NSTEP + 1) * 6 + lane] = bp;
        }
        if (k < NSTEP - 1) {
          double rv = (lane < 6) ? (double)sF[(k+1)*20 + 2 + lane] : 0.0;
          double xv = wave_gauss6(S, rv, lane);
          if (lane < 6) {
            float v = (float)xv;
            out[OUT_ETA + (k + 1) * 6 + lane] = v;
            if (k + 1 == NSTEP - 1) out[OUT_ETA + NSTEP * 6 + lane] = v;
            fst(&COEFP[lane], v * (float)(lane + 1));
          }
          if (lane == 6) fst(&COEFP[6], sF[(k+1) * 20 + 0]);
          if (lane == 7) fst(&COEFP[7], sF[(k+1) * 20 + 1]);
          CFENCE(); WAITVM();
          if (lane < 32) ust(&seqP[lane * 16], (uint32_t)(k + 2));
        }
      }
    }
    return;
  }

  // ============================== WORKER =================================
  const int wb = blockIdx.x - 1;
  const int bidx = blockIdx.x & (NBUCK - 1);
  const int myseq = (blockIdx.x & 31) * 16;
  int f4[2]; bool vld[2];
  float st[8];
  float nz[8];
  if (t < NSTEP) threefry2x32(0u, 42u, 0u, (uint32_t)t, &sK[t][0], &sK[t][1]);
#pragma unroll
  for (int c = 0; c < 2; c++) { f4[c] = (wb * 2 + c) * 256 + t; vld[c] = f4[c] < NF4; }

  // ---- setup: load state + 37 joint/xk moments
  {
    float a37[37];
#pragma unroll
    for (int q = 0; q < 37; q++) a37[q] = 0.f;
#pragma unroll
    for (int c = 0; c < 2; c++) {
      if (vld[c]) {
        float4 xk4 = ((const float4*)xkg)[f4[c]];
        float4 x04 = ((const float4*)x0g)[f4[c]];
        float4 x14 = ((const float4*)x1g)[f4[c]];
        float xk_[4] = {xk4.x, xk4.y, xk4.z, xk4.w};
        float x0_[4] = {x04.x, x04.y, x04.z, x04.w};
        float x1_[4] = {x14.x, x14.y, x14.z, x14.w};
#pragma unroll
        for (int r = 0; r < 4; r++) {
          st[c * 4 + r] = xk_[r];
          float p0[7], p1[7];
          p0[0] = 1.f; p1[0] = 1.f;
#pragma unroll
          for (int m = 0; m < 6; m++) { p0[m+1] = p0[m]*x0_[r]; p1[m+1] = p1[m]*x1_[r]; }
          int q = 0;
#pragma unroll
          for (int s = 1; s <= 6; s++)
#pragma unroll
            for (int a = 0; a <= s; a++) a37[q++] += p0[a] * p1[s - a];
          float xp = xk_[r];
          a37[27] += xp;
#pragma unroll
          for (int m = 1; m < 10; m++) { xp *= xk_[r]; a37[27 + m] += xp; }
        }
      } else {
#pragma unroll
        for (int r = 0; r < 4; r++) st[c * 4 + r] = 0.f;
      }
    }
    block_bucket<37>(a37, JB, smf, lane, wid, t, bidx);
    if (t == 0) { CFENCE(); WAITVM(); uadd(&leaf0[blockIdx.x & 31], 1u); }
  }

  // ---- precompute step-0 noise (overlaps solver's F-table + eta_0 work)
#pragma unroll
  for (int c = 0; c < 2; c++) {
    if (vld[c]) {
      uint32_t base = (uint32_t)(f4[c] * 4);
#pragma unroll
      for (int r = 0; r < 4; r++) {
        uint32_t o0, o1;
        threefry2x32(sK[0][0], sK[0][1], 0u, base + (uint32_t)r, &o0, &o1);
        nz[c * 4 + r] = bits_to_normal(o0 ^ o1);
      }
    }
  }

  // ---- main loop
  for (int k = 0; k < NSTEP; k++) {
    // -- predictor (noise already in nz[])
    if (t == 0) {
      while (uld(&seqP[myseq]) < (uint32_t)(k + 1)) __builtin_amdgcn_s_sleep(2);
      CFENCE();
#pragma unroll
      for (int i = 0; i < 8; i++) sC[i] = fld(&COEFP[i]);
    }
    __syncthreads();
    {
      float c0 = sC[0], c1 = sC[1], c2 = sC[2], c3 = sC[3];
      float c4 = sC[4], c5 = sC[5], h = sC[6], ns = sC[7];
      float acc[10];
#pragma unroll
      for (int q = 0; q < 10; q++) acc[q] = 0.f;
#pragma unroll
      for (int c = 0; c < 2; c++) {
        if (vld[c]) {
#pragma unroll
          for (int r = 0; r < 4; r++) {
            float x = st[c * 4 + r];
            float d = c0 + x*(c1 + x*(c2 + x*(c3 + x*(c4 + x*c5))));
            float y = x + h * d + ns * nz[c * 4 + r];
            st[c * 4 + r] = y;
            float pw = y;
            acc[0] += pw;
#pragma unroll
            for (int m = 1; m < 10; m++) { pw *= y; acc[m] += pw; }
          }
        }
      }
      block_bucket<10>(acc, SYB + k * 10 * NBUCK, smf, lane, wid, t, bidx);
      if (t == 0) { CFENCE(); WAITVM(); uadd(&leafP[blockIdx.x & 31], 1u); }
    }
    // -- precompute half of next step's noise inside the theta-solve window
    if (k + 1 < NSTEP) {
      uint32_t ka = sK[k + 1][0], kb = sK[k + 1][1];
      if (vld[0]) {
        uint32_t base = (uint32_t)(f4[0] * 4);
#pragma unroll
        for (int r = 0; r < 4; r++) {
          uint32_t o0, o1;
          threefry2x32(ka, kb, 0u, base + (uint32_t)r, &o0, &o1);
          nz[r] = bits_to_normal(o0 ^ o1);
        }
      }
    }
    // -- corrector
    if (t == 0) {
      while (uld(&seqC[myseq]) < (uint32_t)(k + 1)) __builtin_amdgcn_s_sleep(2);
      CFENCE();
#pragma unroll
      for (int i = 0; i < 6; i++) sC[i] = fld(&COEFC[i]);
    }
    __syncthreads();
    {
      float c0 = sC[0], c1 = sC[1], c2 = sC[2], c3 = sC[3];
      float c4 = sC[4], c5 = sC[5];
      float acc[10];
#pragma unroll
      for (int q = 0; q < 10; q++) acc[q] = 0.f;
#pragma unroll
      for (int c = 0; c < 2; c++) {
        if (vld[c]) {
#pragma unroll
          for (int r = 0; r < 4; r++) {
            float y = st[c * 4 + r];
            float cr = c0 + y*(c1 + y*(c2 + y*(c3 + y*(c4 + y*c5))));
            float xn = y + cr;
            st[c * 4 + r] = xn;
            float pw = xn;
            acc[0] += pw;
#pragma unroll
            for (int m = 1; m < 10; m++) { pw *= xn; acc[m] += pw; }
          }
        }
      }
      block_bucket<10>(acc, SXB + k * 10 * NBUCK, smf, lane, wid, t, bidx);
      if (t == 0) { CFENCE(); WAITVM(); uadd(&leafC[blockIdx.x & 31], 1u); }
    }
    // -- precompute other half of next step's noise inside the eta-solve window
    if (k + 1 < NSTEP) {
      uint32_t ka = sK[k + 1][0], kb = sK[k + 1][1];
      if (vld[1]) {
        uint32_t base = (uint32_t)(f4[1] * 4);
#pragma unroll
        for (int r = 0; r < 4; r++) {
          uint32_t o0, o1;
          threefry2x32(ka, kb, 0u, base + (uint32_t)r, &o0, &o1);
          nz[4 + r] = bits_to_normal(o0 ^ o1);
        }
      }
    }
  }

  // ---- write x_final
#pragma unroll
  for (int c = 0; c < 2; c++) {
    if (vld[c]) {
      ((float4*)out)[f4[c]] =
          make_float4(st[c*4+0], st[c*4+1], st[c*4+2], st[c*4+3]);
    }
  }
}

extern "C" void kernel_launch(void* const* d_in, const int* in_sizes, int n_in,
                              void* d_out, int out_size, void* d_ws, size_t ws_size,
                              hipStream_t stream) {
  const float* x1 = (const float*)d_in[0];
  const float* x0 = (const float*)d_in[1];
  const float* xk = (const float*)d_in[2];
  const float* t  = (const float*)d_in[3];
  float* out = (float*)d_out;

  double* WD = (double*)d_ws;
  uint32_t* WU = (uint32_t*)(WD + O_END);

  hipMemsetAsync(d_ws, 0, (size_t)WS_BYTES, stream);
  k_all<<<GRID, BLKSZ, 0, stream>>>(x1, x0, xk, t, out, WD, WU);
}

// Round 11
// 730.757 us; speedup vs baseline: 1.5786x; 1.5786x over previous
//
#include <hip/hip_runtime.h>
#include <stdint.h>

#define N_SAMP  2000000
#define NF4     500000          // float4 groups
#define NSTEP   32
#define INV_N   (1.0/2000000.0)
#define NBUCK   64
#define GRID    512
#define NWORK   511
#define BLKSZ   256

#define OUT_BE  2000000
#define OUT_BP  2000204
#define OUT_ETA 2000408
#define OUT_TH  2000606
#define OUT_DH  2000804

// ws doubles layout
#define O_JB    0
#define O_SYB   (37*NBUCK)
#define O_SXB   (O_SYB + NSTEP*10*NBUCK)
#define O_END   (O_SXB + NSTEP*10*NBUCK)
// u32 region: [32..63] leaf0, [64..95] leafP, [96..127] leafC
// then 128 u64 tagged-coef words: COEFP 8 replicas x 8, COEFC 8 replicas x 8
#define WS_BYTES (O_END*8 + 128*4 + 128*8)

#define CFENCE() __atomic_signal_fence(__ATOMIC_SEQ_CST)
#define WAITVM() __builtin_amdgcn_s_waitcnt(0)

__device__ inline uint32_t uld(const uint32_t* p) {
  return __hip_atomic_load(p, __ATOMIC_RELAXED, __HIP_MEMORY_SCOPE_AGENT);
}
__device__ inline void uadd(uint32_t* p, uint32_t v) {
  __hip_atomic_fetch_add(p, v, __ATOMIC_RELAXED, __HIP_MEMORY_SCOPE_AGENT);
}
__device__ inline double dld(const double* p) {
  return __hip_atomic_load(p, __ATOMIC_RELAXED, __HIP_MEMORY_SCOPE_AGENT);
}
__device__ inline unsigned long long ald64(const unsigned long long* p) {
  return __hip_atomic_load(p, __ATOMIC_RELAXED, __HIP_MEMORY_SCOPE_AGENT);
}
__device__ inline void ast64(unsigned long long* p, unsigned long long v) {
  __hip_atomic_store(p, v, __ATOMIC_RELAXED, __HIP_MEMORY_SCOPE_AGENT);
}

// ---------------- threefry2x32 core cipher, bit-exact vs JAX ----------------
__host__ __device__ inline void threefry2x32(uint32_t k0, uint32_t k1,
                                             uint32_t c0, uint32_t c1,
                                             uint32_t* o0, uint32_t* o1) {
  uint32_t ks2 = k0 ^ k1 ^ 0x1BD11BDAu;
  uint32_t x0 = c0 + k0;
  uint32_t x1 = c1 + k1;
#define TF_ROT(x, d) (((x) << (d)) | ((x) >> (32 - (d))))
#define TF_R(a,b,c,d, ka, kb, inc) \
  x0 += x1; x1 = TF_ROT(x1, a); x1 ^= x0; \
  x0 += x1; x1 = TF_ROT(x1, b); x1 ^= x0; \
  x0 += x1; x1 = TF_ROT(x1, c); x1 ^= x0; \
  x0 += x1; x1 = TF_ROT(x1, d); x1 ^= x0; \
  x0 += (ka); x1 += (kb) + (inc);
  TF_R(13,15,26,6,  k1,  ks2, 1u)
  TF_R(17,29,16,24, ks2, k0,  2u)
  TF_R(13,15,26,6,  k0,  k1,  3u)
  TF_R(17,29,16,24, k1,  ks2, 4u)
  TF_R(13,15,26,6,  ks2, k0,  5u)
#undef TF_R
#undef TF_ROT
  *o0 = x0; *o1 = x1;
}

// bits -> N(0,1), jax.random.normal f32 path (partitionable bits pre-XOR-folded)
__device__ inline float bits_to_normal(uint32_t bits) {
  float f = __uint_as_float((bits >> 9) | 0x3f800000u) - 1.0f;
  const float lo = -0.99999994f;
  float u = f * 2.0f + lo;
  u = fmaxf(lo, u);
  float w = -log1pf(-u * u);
  float p;
  if (w < 5.0f) {
    w = w - 2.5f;
    p = 2.81022636e-08f;
    p = fmaf(p, w, 3.43273939e-07f);
    p = fmaf(p, w, -3.5233877e-06f);
    p = fmaf(p, w, -4.39150654e-06f);
    p = fmaf(p, w, 0.00021858087f);
    p = fmaf(p, w, -0.00125372503f);
    p = fmaf(p, w, -0.00417768164f);
    p = fmaf(p, w, 0.246640727f);
    p = fmaf(p, w, 1.50140941f);
  } else {
    w = sqrtf(w) - 3.0f;
    p = -0.000200214257f;
    p = fmaf(p, w, 0.000100950558f);
    p = fmaf(p, w, 0.00134934322f);
    p = fmaf(p, w, -0.00367342844f);
    p = fmaf(p, w, 0.00573950773f);
    p = fmaf(p, w, -0.0076224613f);
    p = fmaf(p, w, 0.00943887047f);
    p = fmaf(p, w, 1.00167406f);
    p = fmaf(p, w, 2.83297682f);
  }
  return __uint_as_float(0x3FB504F3u) * (p * u);
}

// lane-distributed 6x6 Gaussian elimination (wave 0). S replicated; rv = rhs
// for lane<6. Lane r<6 returns solution[r].
__device__ inline double wave_gauss6(const double S[11], double rv, int lane) {
  int r = (lane < 6) ? lane : 0;
  double row[6];
#pragma unroll
  for (int j = 0; j < 6; j++) row[j] = (double)((r + 1) * (j + 1)) * S[r + j];
  row[r] *= 1.001;                        // REG = (1e-3, 0, 0)
#pragma unroll
  for (int c = 0; c < 6; c++) {
    double pr[6], prh;
#pragma unroll
    for (int j = 0; j < 6; j++) pr[j] = __shfl(row[j], c, 64);
    prh = __shfl(rv, c, 64);
    if (lane > c && lane < 6) {
      double f = row[c] / pr[c];
#pragma unroll
      for (int j = 0; j < 6; j++) row[j] -= f * pr[j];
      rv -= f * prh;
    }
  }
  double xv = 0.0;
#pragma unroll
  for (int rr = 5; rr >= 0; rr--) {
    double cand = rv / row[rr];
    double xr = __shfl(cand, rr, 64);
    if (lane == rr) xv = xr;
    if (lane < rr) rv -= row[rr] * xr;
  }
  return xv;
}

// solver: wait until sum of 32 leaf counters reaches target
__device__ inline void wait_leaves(const uint32_t* leaf, uint32_t target, int lane) {
  for (;;) {
    uint32_t v = uld(&leaf[lane & 31]);
#pragma unroll
    for (int off = 16; off; off >>= 1) v += __shfl_xor(v, off, 64);
    if (v >= target) break;
    __builtin_amdgcn_s_sleep(2);
  }
  CFENCE();
}

// solver: replicated mean-moments from 64 buckets x 10 quantities
__device__ inline void get_S(const double* B, int lane, double S[11]) {
  S[0] = 1.0;
#pragma unroll
  for (int q = 0; q < 10; q++) {
    double s = dld(&B[q * NBUCK + lane]);
#pragma unroll
    for (int off = 32; off; off >>= 1) s += __shfl_xor(s, off, 64);
    S[q + 1] = s * INV_N;
  }
}

// solver: publish 8 tagged words to 8 replicas (64 lanes: rep=lane>>3, i=lane&7)
__device__ inline void publish8(unsigned long long* base, int lane,
                                uint32_t tag, float val) {
  int i = lane & 7, rep = lane >> 3;
  unsigned long long w =
      ((unsigned long long)tag << 32) | (unsigned long long)__float_as_uint(val);
  ast64(&base[(size_t)rep * 8 + i], w);
}

// worker: f32 block-reduce of NQ quantities -> f64 bucket atomics (t<NQ)
template <int NQ>
__device__ inline void block_bucket(float acc[NQ], double* __restrict__ buck,
                                    float smf[4][37], int lane, int wid, int t,
                                    int bidx) {
#pragma unroll
  for (int q = 0; q < NQ; q++) {
    float v = acc[q];
#pragma unroll
    for (int off = 32; off; off >>= 1) v += __shfl_down(v, off, 64);
    if (lane == 0) smf[wid][q] = v;
  }
  __syncthreads();
  if (t < NQ) {
    double s = (double)smf[0][t] + (double)smf[1][t] +
               (double)smf[2][t] + (double)smf[3][t];
    atomicAdd(&buck[t * NBUCK + bidx], s);
  }
}

// worker: single-RT tagged poll into sC (t==0), then broadcast
__device__ inline void poll_coefs(const unsigned long long* cp, uint32_t want,
                                  float* sC, int t) {
  if (t == 0) {
    for (;;) {
      unsigned long long w[8];
#pragma unroll
      for (int i = 0; i < 8; i++) w[i] = ald64(&cp[i]);
      bool ok = true;
#pragma unroll
      for (int i = 0; i < 8; i++) ok = ok && ((uint32_t)(w[i] >> 32) == want);
      if (ok) {
#pragma unroll
        for (int i = 0; i < 8; i++) sC[i] = __uint_as_float((uint32_t)w[i]);
        break;
      }
      __builtin_amdgcn_s_sleep(2);
    }
  }
  __syncthreads();
}

// tree-structured powers: acc[m-1] += y^m, m=1..10 (dep depth 4)
__device__ inline void acc_moments(float y, float acc[10]) {
  float p2 = y * y;
  float p3 = p2 * y, p4 = p2 * p2;
  float p5 = p3 * p2, p6 = p3 * p3, p7 = p4 * p3, p8 = p4 * p4;
  float p9 = p5 * p4, p10 = p5 * p5;
  acc[0] += y;  acc[1] += p2; acc[2] += p3; acc[3] += p4; acc[4] += p5;
  acc[5] += p6; acc[6] += p7; acc[7] += p8; acc[8] += p9; acc[9] += p10;
}

__global__ __launch_bounds__(BLKSZ, 2) void k_all(
    const float* __restrict__ x1g, const float* __restrict__ x0g,
    const float* __restrict__ xkg, const float* __restrict__ tg,
    float* __restrict__ out, double* __restrict__ WD, uint32_t* __restrict__ WU) {
  __shared__ float smf[4][37];
  __shared__ float sC[8];
  __shared__ double sMsc[37];
  __shared__ float sF[NSTEP * 20];
  __shared__ uint32_t sK[NSTEP][2];

  const int t = threadIdx.x;
  const int lane = t & 63, wid = t >> 6;
  double* JB  = WD + O_JB;
  double* SYB = WD + O_SYB;
  double* SXB = WD + O_SXB;
  uint32_t* leaf0 = WU + 32;
  uint32_t* leafP = WU + 64;
  uint32_t* leafC = WU + 96;
  unsigned long long* C64  = (unsigned long long*)(WU + 128);
  unsigned long long* C64P = C64;        // 8 replicas x 8 words
  unsigned long long* C64C = C64 + 64;   // 8 replicas x 8 words

  if (blockIdx.x == 0) {
    // =========================== SOLVER (wave 0) ===========================
    if (t >= 64) return;
    wait_leaves(leaf0, NWORK, lane);
    for (int q = 0; q < 37; q++) {
      double s = dld(&JB[q * NBUCK + lane]);
#pragma unroll
      for (int off = 32; off; off >>= 1) s += __shfl_xor(s, off, 64);
      if (lane == 0) sMsc[q] = s * INV_N;
    }
#define MG(A, B_) (((A) == 0 && (B_) == 0) ? 1.0 : \
    sMsc[(((A) + (B_) + 2) * ((A) + (B_) - 1)) / 2 + (A)])
    if (lane < NSTEP) {
      const double Bd[7][7] = {
          {1,0,0,0,0,0,0},{1,1,0,0,0,0,0},{1,2,1,0,0,0,0},{1,3,3,1,0,0,0},
          {1,4,6,4,1,0,0},{1,5,10,10,5,1,0},{1,6,15,20,15,6,1}};
      int k = lane;
      float tk = tg[k], tk1 = tg[k + 1];
      float h = tk1 - tk;
      float ns = sqrtf(2.0f * h) * 0.5f;
      const float PI_F = 3.14159274f;
      double a  = (double)cosf((PI_F * tk) * 0.5f);
      double b  = (double)sinf((PI_F * tk) * 0.5f);
      double a1 = (double)cosf((PI_F * tk1) * 0.5f);
      double b1 = (double)sinf((PI_F * tk1) * 0.5f);
      const double C2 = (double)1.57079637f;
      double pa[7], pb[7], pa1[7], pb1[7];
      pa[0] = pb[0] = pa1[0] = pb1[0] = 1.0;
      for (int i = 1; i < 7; i++) {
        pa[i] = pa[i-1] * a;   pb[i] = pb[i-1] * b;
        pa1[i] = pa1[i-1] * a1; pb1[i] = pb1[i-1] * b1;
      }
      sF[k * 20 + 0] = h;
      sF[k * 20 + 1] = ns;
      for (int p = 1; p <= 6; p++) {
        double s_rhs = 0, s_bpe = 0, s_dt = 0;
        for (int j = 0; j < p; j++) {
          double term = -b * MG(j + 1, p - 1 - j) + a * MG(j, p - j);
          s_rhs += Bd[p-1][j] * pa[j]  * pb[p-1-j]  * term;
          s_dt  += Bd[p-1][j] * pa1[j] * pb1[p-1-j] * term;
        }
        for (int j = 0; j <= p; j++)
          s_bpe += Bd[p][j] * pa1[j] * pb1[p - j] * MG(j, p - j);
        float fr = (float)((double)p * C2 * s_rhs);
        float be = (float)s_bpe;
        sF[k * 20 + 2 + p - 1]  = fr;
        sF[k * 20 + 8 + p - 1]  = be;
        sF[k * 20 + 14 + p - 1] = (float)((double)p * C2 * s_dt);
        out[OUT_BE + (k + 1) * 6 + (p - 1)] = be;
        if (k == NSTEP - 1) out[OUT_BE + (NSTEP + 1) * 6 + (p - 1)] = be;
      }
    }
    // eta_0 solve + publish step-0 pred coefs FIRST, bookkeeping after
    {
      double S[11];
      S[0] = 1.0;
#pragma unroll
      for (int q = 0; q < 10; q++) S[q + 1] = sMsc[27 + q];
      double rv = (lane < 6) ? (double)sF[2 + lane] : 0.0;
      double xv = wave_gauss6(S, rv, lane);
      int i = lane & 7;
      float xs = (float)__shfl(xv, i, 64);
      float val = (i < 6) ? xs * (float)(i + 1) : ((i == 6) ? sF[0] : sF[1]);
      publish8(C64P, lane, 1u, val);
      if (lane < 6) out[OUT_ETA + lane] = (float)xv;
    }
    if (lane < 6) {
      int p = lane + 1;
      out[OUT_BE + lane] = (float)MG(p, 0);
      out[OUT_BP + lane] = (float)sMsc[27 + lane];
    }
#undef MG
    for (int k = 0; k < NSTEP; k++) {
      // theta solve after all pred buckets of step k
      wait_leaves(leafP, (uint32_t)(NWORK * (k + 1)), lane);
      {
        double S[11];
        get_S(SYB + k * 10 * NBUCK, lane, S);
        double rv = (lane < 6) ? ((double)sF[k*20 + 8 + lane] - S[lane + 1]) : 0.0;
        double xv = wave_gauss6(S, rv, lane);
        int i = lane & 7;
        float xs = (float)__shfl(xv, i, 64);
        float val = (i < 6) ? xs * (float)(i + 1) : 0.f;
        publish8(C64C, lane, (uint32_t)(k + 1), val);
        // bookkeeping after publish
        float h = sF[k * 20];
        float th = (float)xv / (h * 0.25f);
        if (lane < 6) {
          out[OUT_TH + k * 6 + lane] = th;
          if (k == NSTEP - 1) out[OUT_TH + NSTEP * 6 + lane] = th;
        }
        float contrib = (lane < 6) ? th * sF[k*20 + 14 + lane] : 0.f;
#pragma unroll
        for (int off = 4; off; off >>= 1) contrib += __shfl_down(contrib, off, 64);
        if (lane == 0) {
          float dH = -contrib;
          out[OUT_DH + k] = dH;
          if (k == NSTEP - 1) out[OUT_DH + NSTEP] = dH;
        }
      }
      // eta_{k+1} solve after all corr buckets of step k
      wait_leaves(leafC, (uint32_t)(NWORK * (k + 1)), lane);
      {
        double S[11];
        get_S(SXB + k * 10 * NBUCK, lane, S);
        if (k < NSTEP - 1) {
          double rv = (lane < 6) ? (double)sF[(k+1)*20 + 2 + lane] : 0.0;
          double xv = wave_gauss6(S, rv, lane);
          int i = lane & 7;
          float xs = (float)__shfl(xv, i, 64);
          float val = (i < 6) ? xs * (float)(i + 1)
                              : ((i == 6) ? sF[(k+1)*20 + 0] : sF[(k+1)*20 + 1]);
          publish8(C64P, lane, (uint32_t)(k + 2), val);
          if (lane < 6) {
            float v = (float)xv;
            out[OUT_ETA + (k + 1) * 6 + lane] = v;
            if (k + 1 == NSTEP - 1) out[OUT_ETA + NSTEP * 6 + lane] = v;
          }
        }
        if (lane < 6) {
          float bp = (float)S[lane + 1];
          out[OUT_BP + (k + 1) * 6 + lane] = bp;
          if (k == NSTEP - 1) out[OUT_BP + (NSTEP + 1) * 6 + lane] = bp;
        }
      }
    }
    return;
  }

  // ============================== WORKER =================================
  const int wb = blockIdx.x - 1;
  const int bidx = blockIdx.x & (NBUCK - 1);
  const unsigned long long* myP = C64P + (size_t)(blockIdx.x & 7) * 8;
  const unsigned long long* myC = C64C + (size_t)(blockIdx.x & 7) * 8;
  int f4[4]; bool vld[4];
  float st[16];
  float nz[16];
  if (t < NSTEP) threefry2x32(0u, 42u, 0u, (uint32_t)t, &sK[t][0], &sK[t][1]);
#pragma unroll
  for (int c = 0; c < 4; c++) { f4[c] = (wb * 4 + c) * 256 + t; vld[c] = f4[c] < NF4; }

  // ---- setup: load state + 37 joint/xk moments
  {
    float a37[37];
#pragma unroll
    for (int q = 0; q < 37; q++) a37[q] = 0.f;
#pragma unroll
    for (int c = 0; c < 4; c++) {
      if (vld[c]) {
        float4 xk4 = ((const float4*)xkg)[f4[c]];
        float4 x04 = ((const float4*)x0g)[f4[c]];
        float4 x14 = ((const float4*)x1g)[f4[c]];
        float xk_[4] = {xk4.x, xk4.y, xk4.z, xk4.w};
        float x0_[4] = {x04.x, x04.y, x04.z, x04.w};
        float x1_[4] = {x14.x, x14.y, x14.z, x14.w};
#pragma unroll
        for (int r = 0; r < 4; r++) {
          st[c * 4 + r] = xk_[r];
          float p0[7], p1[7];
          p0[0] = 1.f; p1[0] = 1.f;
#pragma unroll
          for (int m = 0; m < 6; m++) { p0[m+1] = p0[m]*x0_[r]; p1[m+1] = p1[m]*x1_[r]; }
          int q = 0;
#pragma unroll
          for (int s = 1; s <= 6; s++)
#pragma unroll
            for (int a = 0; a <= s; a++) a37[q++] += p0[a] * p1[s - a];
          float xp = xk_[r];
          a37[27] += xp;
#pragma unroll
          for (int m = 1; m < 10; m++) { xp *= xk_[r]; a37[27 + m] += xp; }
        }
      } else {
#pragma unroll
        for (int r = 0; r < 4; r++) st[c * 4 + r] = 0.f;
      }
    }
    block_bucket<37>(a37, JB, smf, lane, wid, t, bidx);
    if (t == 0) { CFENCE(); WAITVM(); uadd(&leaf0[blockIdx.x & 31], 1u); }
  }

  // ---- precompute step-0 noise (overlaps solver's F-table + eta_0 work)
#pragma unroll
  for (int c = 0; c < 4; c++) {
    if (vld[c]) {
      uint32_t base = (uint32_t)(f4[c] * 4);
#pragma unroll
      for (int r = 0; r < 4; r++) {
        uint32_t o0, o1;
        threefry2x32(sK[0][0], sK[0][1], 0u, base + (uint32_t)r, &o0, &o1);
        nz[c * 4 + r] = bits_to_normal(o0 ^ o1);
      }
    }
  }

  // ---- main loop
  for (int k = 0; k < NSTEP; k++) {
    // -- predictor (noise already in nz[])
    poll_coefs(myP, (uint32_t)(k + 1), sC, t);
    {
      float c0 = sC[0], c1 = sC[1], c2 = sC[2], c3 = sC[3];
      float c4 = sC[4], c5 = sC[5], h = sC[6], ns = sC[7];
      float acc[10];
#pragma unroll
      for (int q = 0; q < 10; q++) acc[q] = 0.f;
#pragma unroll
      for (int c = 0; c < 4; c++) {
        if (vld[c]) {
#pragma unroll
          for (int r = 0; r < 4; r++) {
            float x = st[c * 4 + r];
            float d = c0 + x*(c1 + x*(c2 + x*(c3 + x*(c4 + x*c5))));
            float y = x + h * d + ns * nz[c * 4 + r];
            st[c * 4 + r] = y;
            acc_moments(y, acc);
          }
        }
      }
      block_bucket<10>(acc, SYB + k * 10 * NBUCK, smf, lane, wid, t, bidx);
      if (t == 0) { CFENCE(); WAITVM(); uadd(&leafP[blockIdx.x & 31], 1u); }
    }
    // -- half of next step's noise inside the theta-solve window
    if (k + 1 < NSTEP) {
      uint32_t ka = sK[k + 1][0], kb = sK[k + 1][1];
#pragma unroll
      for (int c = 0; c < 2; c++) {
        if (vld[c]) {
          uint32_t base = (uint32_t)(f4[c] * 4);
#pragma unroll
          for (int r = 0; r < 4; r++) {
            uint32_t o0, o1;
            threefry2x32(ka, kb, 0u, base + (uint32_t)r, &o0, &o1);
            nz[c * 4 + r] = bits_to_normal(o0 ^ o1);
          }
        }
      }
    }
    // -- corrector
    poll_coefs(myC, (uint32_t)(k + 1), sC, t);
    {
      float c0 = sC[0], c1 = sC[1], c2 = sC[2], c3 = sC[3];
      float c4 = sC[4], c5 = sC[5];
      float acc[10];
#pragma unroll
      for (int q = 0; q < 10; q++) acc[q] = 0.f;
#pragma unroll
      for (int c = 0; c < 4; c++) {
        if (vld[c]) {
#pragma unroll
          for (int r = 0; r < 4; r++) {
            float y = st[c * 4 + r];
            float cr = c0 + y*(c1 + y*(c2 + y*(c3 + y*(c4 + y*c5))));
            float xn = y + cr;
            st[c * 4 + r] = xn;
            acc_moments(xn, acc);
          }
        }
      }
      block_bucket<10>(acc, SXB + k * 10 * NBUCK, smf, lane, wid, t, bidx);
      if (t == 0) { CFENCE(); WAITVM(); uadd(&leafC[blockIdx.x & 31], 1u); }
    }
    // -- other half of next step's noise inside the eta-solve window
    if (k + 1 < NSTEP) {
      uint32_t ka = sK[k + 1][0], kb = sK[k + 1][1];
#pragma unroll
      for (int c = 2; c < 4; c++) {
        if (vld[c]) {
          uint32_t base = (uint32_t)(f4[c] * 4);
#pragma unroll
          for (int r = 0; r < 4; r++) {
            uint32_t o0, o1;
            threefry2x32(ka, kb, 0u, base + (uint32_t)r, &o0, &o1);
            nz[c * 4 + r] = bits_to_normal(o0 ^ o1);
          }
        }
      }
    }
  }

  // ---- write x_final
#pragma unroll
  for (int c = 0; c < 4; c++) {
    if (vld[c]) {
      ((float4*)out)[f4[c]] =
          make_float4(st[c*4+0], st[c*4+1], st[c*4+2], st[c*4+3]);
    }
  }
}

extern "C" void kernel_launch(void* const* d_in, const int* in_sizes, int n_in,
                              void* d_out, int out_size, void* d_ws, size_t ws_size,
                              hipStream_t stream) {
  const float* x1 = (const float*)d_in[0];
  const float* x0 = (const float*)d_in[1];
  const float* xk = (const float*)d_in[2];
  const float* t  = (const float*)d_in[3];
  float* out = (float*)d_out;

  double* WD = (double*)d_ws;
  uint32_t* WU = (uint32_t*)(WD + O_END);

  hipMemsetAsync(d_ws, 0, (size_t)WS_BYTES, stream);
  k_all<<<GRID, BLKSZ, 0, stream>>>(x1, x0, xk, t, out, WD, WU);
}